// Round 4
// baseline (503.752 us; speedup 1.0000x reference)
//
#include <hip/hip_runtime.h>
#include <hip/hip_bf16.h>
#include <stdint.h>

#define B_   8
#define SQ_  2048
#define SK_  2048
#define D_   1024
#define DV_  1024

typedef __bf16 bf16;
typedef __attribute__((ext_vector_type(4))) __bf16 bf16x4;
typedef __attribute__((ext_vector_type(8))) __bf16 bf16x8;
typedef __attribute__((ext_vector_type(4))) float  f32x4;

// Async global->LDS, 16 B per lane (global_load_lds_dwordx4). LDS dest is
// wave-uniform base + lane*16 (m97 pattern) — layout must be contiguous.
__device__ __forceinline__ void async_cp16(const void* g, void* l) {
    __builtin_amdgcn_global_load_lds((const __attribute__((address_space(1))) void*)g,
                                     (__attribute__((address_space(3))) void*)l,
                                     16, 0, 0);
}

// ---------------------------------------------------------------------------
// K0: V (fp32, [b][k][n]) -> Vt (bf16, [b][n][k]) in workspace. 64x64 tiles.
// Makes context a pure gemm-bt (both operands row-major over the k dim).
// ---------------------------------------------------------------------------
__global__ __launch_bounds__(256)
void vtrans_kernel(const float* __restrict__ V, bf16* __restrict__ Vt)
{
    const int b  = blockIdx.z;
    const int n0 = blockIdx.y * 64;
    const int k0 = blockIdx.x * 64;
    __shared__ float L[64][65];          // 65: scalar stores, 4-way read conflicts max
    const int tid = threadIdx.x;
    const float* Vb = V + (size_t)b * SK_ * DV_;
    #pragma unroll
    for (int i = 0; i < 4; ++i) {
        int s = tid + i * 256;
        int kr = s >> 4, n4 = (s & 15) << 2;
        float4 v = *(const float4*)(Vb + (size_t)(k0 + kr) * DV_ + n0 + n4);
        L[kr][n4 + 0] = v.x; L[kr][n4 + 1] = v.y;
        L[kr][n4 + 2] = v.z; L[kr][n4 + 3] = v.w;
    }
    __syncthreads();
    bf16* Vtb = Vt + (size_t)b * DV_ * SK_;
    #pragma unroll
    for (int i = 0; i < 2; ++i) {
        int u = tid + i * 256;
        int nr = u >> 3, kc = (u & 7) << 3;
        bf16x8 o = { (bf16)L[kc + 0][nr], (bf16)L[kc + 1][nr],
                     (bf16)L[kc + 2][nr], (bf16)L[kc + 3][nr],
                     (bf16)L[kc + 4][nr], (bf16)L[kc + 5][nr],
                     (bf16)L[kc + 6][nr], (bf16)L[kc + 7][nr] };
        *(bf16x8*)(Vtb + (size_t)(n0 + nr) * SK_ + k0 + kc) = o;
    }
}

// ---------------------------------------------------------------------------
// K1: raw scaled scores S = Q K^T / 32, unmasked, into weights region.
// 64x64 tiles (round-1 size, round-3 pipeline): only ~343 128-blocks were
// live (1.3/CU, latency-starved at Occupancy 5.6%); 64-tiles give ~1250 live
// blocks (~5/CU). Reg-prefetch double buffer kept.
// ---------------------------------------------------------------------------
__global__ __launch_bounds__(256)
void scores_kernel(const float* __restrict__ Q, const float* __restrict__ K,
                   const int* __restrict__ qlens, const int* __restrict__ klens,
                   float* __restrict__ Wout)
{
    const int b  = blockIdx.z;
    const int q0 = blockIdx.y * 64;
    const int k0 = blockIdx.x * 64;
    if (k0 > q0 + 63) return;                    // fully above causal diagonal
    const int qlen = qlens[b], klen = klens[b];
    if (q0 >= qlen || k0 >= klen) return;        // fully masked

    __shared__ __align__(16) bf16 Qs[2][64][72];
    __shared__ __align__(16) bf16 Ks[2][64][72];

    const int tid  = threadIdx.x;
    const int lane = tid & 63;
    const int w    = tid >> 6;                   // wave 0..3, owns 16q x 64k

    const float* Qb = Q + (size_t)b * SQ_ * D_;
    const float* Kb = K + (size_t)b * SK_ * D_;

    float4 qreg[4], kreg[4];
    int srow[4], sc4[4];
    #pragma unroll
    for (int i = 0; i < 4; ++i) {
        int s = tid + i * 256;                   // 1024 float4 slots per matrix
        srow[i] = s >> 4;
        sc4[i]  = (s & 15) << 2;
    }

    auto load_tile = [&](int d0) {
        #pragma unroll
        for (int i = 0; i < 4; ++i) {
            qreg[i] = *(const float4*)(Qb + (size_t)(q0 + srow[i]) * D_ + d0 + sc4[i]);
            kreg[i] = *(const float4*)(Kb + (size_t)(k0 + srow[i]) * D_ + d0 + sc4[i]);
        }
    };
    auto store_tile = [&](int buf) {
        #pragma unroll
        for (int i = 0; i < 4; ++i) {
            bf16x4 qb = { (bf16)qreg[i].x, (bf16)qreg[i].y, (bf16)qreg[i].z, (bf16)qreg[i].w };
            bf16x4 kb = { (bf16)kreg[i].x, (bf16)kreg[i].y, (bf16)kreg[i].z, (bf16)kreg[i].w };
            *(bf16x4*)&Qs[buf][srow[i]][sc4[i]] = qb;
            *(bf16x4*)&Ks[buf][srow[i]][sc4[i]] = kb;
        }
    };

    f32x4 acc[4] = {};                           // 16q x 64k per wave

    load_tile(0);
    store_tile(0);
    __syncthreads();

    for (int it = 0; it < 16; ++it) {
        const int cur = it & 1;
        if (it < 15) load_tile((it + 1) * 64);   // prefetch next d-chunk
        #pragma unroll
        for (int kk = 0; kk < 2; ++kk) {
            const int koff = kk * 32 + ((lane >> 4) << 3);
            bf16x8 a = *(const bf16x8*)&Qs[cur][16 * w + (lane & 15)][koff];
            #pragma unroll
            for (int n = 0; n < 4; ++n) {
                bf16x8 bb = *(const bf16x8*)&Ks[cur][16 * n + (lane & 15)][koff];
                acc[n] = __builtin_amdgcn_mfma_f32_16x16x32_bf16(a, bb, acc[n], 0, 0, 0);
            }
        }
        if (it < 15) store_tile(1 - cur);
        __syncthreads();
    }

    float* Wb = Wout + (size_t)b * SQ_ * SK_;
    const int rb = q0 + 16 * w + ((lane >> 4) << 2);   // row = (lane>>4)*4+reg
    const int cb = k0 + (lane & 15);                   // col = lane&15
    #pragma unroll
    for (int n = 0; n < 4; ++n)
        #pragma unroll
        for (int r = 0; r < 4; ++r)
            Wb[(size_t)(rb + r) * SK_ + (cb + 16 * n)] = acc[n][r] * 0.03125f;
}

// ---------------------------------------------------------------------------
// K2: masked softmax in place + bf16 copy into workspace (so K3 stages W
// with async 16B loads instead of fp32+cvt: -210 MB read for +64 MB write).
// ---------------------------------------------------------------------------
__global__ __launch_bounds__(256)
void softmax_kernel(const int* __restrict__ qlens, const int* __restrict__ klens,
                    float* __restrict__ W, bf16* __restrict__ Wb16)
{
    const int bq = blockIdx.x;          // b*SQ + q
    const int b  = bq >> 11;
    const int q  = bq & 2047;
    const int qlen = qlens[b], klen = klens[b];
    int kmax = 0;
    if (q < qlen) kmax = min(klen, q + 1);   // valid cols: k < klen && k <= q

    float4* row = (float4*)(W + (size_t)bq * SK_);
    bf16*  rowb = Wb16 + (size_t)bq * SK_;
    const int tid = threadIdx.x;

    float4 x[2];
    float m = -INFINITY;
    #pragma unroll
    for (int i = 0; i < 2; ++i) {
        int v4 = tid + i * 256;
        int kb = v4 << 2;
        if (kb < kmax) x[i] = row[v4];       // only read live region
        else           x[i] = make_float4(-INFINITY, -INFINITY, -INFINITY, -INFINITY);
        float* xe = (float*)&x[i];
        #pragma unroll
        for (int e = 0; e < 4; ++e) {
            if (kb + e >= kmax) xe[e] = -INFINITY;
            m = fmaxf(m, xe[e]);
        }
    }
    #pragma unroll
    for (int off = 32; off > 0; off >>= 1) m = fmaxf(m, __shfl_xor(m, off, 64));
    __shared__ float red[4];
    if ((tid & 63) == 0) red[tid >> 6] = m;
    __syncthreads();
    m = fmaxf(fmaxf(red[0], red[1]), fmaxf(red[2], red[3]));
    __syncthreads();

    float sum = 0.f;
    #pragma unroll
    for (int i = 0; i < 2; ++i) {
        float* xe = (float*)&x[i];
        #pragma unroll
        for (int e = 0; e < 4; ++e) {
            float ev = (xe[e] == -INFINITY) ? 0.f : __expf(xe[e] - m);
            xe[e] = ev;
            sum += ev;
        }
    }
    #pragma unroll
    for (int off = 32; off > 0; off >>= 1) sum += __shfl_xor(sum, off, 64);
    if ((tid & 63) == 0) red[tid >> 6] = sum;
    __syncthreads();
    sum = red[0] + red[1] + red[2] + red[3];

    const float inv = (sum > 0.f) ? (1.f / sum) : 0.f;   // fully-masked -> 0
    #pragma unroll
    for (int i = 0; i < 2; ++i) {
        float* xe = (float*)&x[i];
        float4 o = { xe[0] * inv, xe[1] * inv, xe[2] * inv, xe[3] * inv };
        row[tid + i * 256] = o;
        bf16x4 ob = { (bf16)o.x, (bf16)o.y, (bf16)o.z, (bf16)o.w };
        *(bf16x4*)(rowb + (size_t)(tid + i * 256) * 4) = ob;
    }
}

// ---------------------------------------------------------------------------
// K3: context = W @ V, m97-style gemm-bt. A = Wb16[q][k], B = Vt[n][k], both
// bf16 row-major over k, staged with global_load_lds width-16 into unpadded
// LDS. Single-barrier double-buffer: next-tile async loads are issued after
// the barrier and fly during MFMA (the vmcnt(0)-before-barrier drains only
// the current tile's loads).
// ---------------------------------------------------------------------------
__global__ __launch_bounds__(512)
void context_kernel(const bf16* __restrict__ Wb16, const bf16* __restrict__ Vt,
                    const int* __restrict__ klens, float* __restrict__ Out)
{
    const int b  = blockIdx.z;
    const int q0 = blockIdx.y * 128;
    const int n0 = blockIdx.x * 128;
    const int klen = klens[b];
    const int kend = min(q0 + 128, (klen + 63) & ~63);
    const int nk   = kend >> 6;                  // 1..32

    __shared__ __align__(16) bf16 As[2][128][64];   // W tile  (q x k)
    __shared__ __align__(16) bf16 Bs[2][128][64];   // Vt tile (n x k)

    const int tid  = threadIdx.x;
    const int lane = tid & 63;
    const int w    = tid >> 6;                   // 0..7
    const int wq   = w >> 1, wn = w & 1;         // 4x2 wave grid, wave 32x64

    const bf16* Ab = Wb16 + (size_t)b * SQ_ * SK_;
    const bf16* Bb = Vt   + (size_t)b * DV_ * SK_;

    // async staging: lane covers row (i*64 + w*8 + lane/8), 16 B at col (lane%8)*8
    const int lrow = w * 8 + (lane >> 3);
    const int lcol = (lane & 7) << 3;

    auto issue = [&](int buf, int k0) {
        #pragma unroll
        for (int i = 0; i < 2; ++i) {
            async_cp16(Ab + (size_t)(q0 + i * 64 + lrow) * SK_ + k0 + lcol,
                       &As[buf][i * 64 + w * 8][0]);
            async_cp16(Bb + (size_t)(n0 + i * 64 + lrow) * SK_ + k0 + lcol,
                       &Bs[buf][i * 64 + w * 8][0]);
        }
    };

    f32x4 acc[2][4] = {};

    issue(0, 0);
    for (int it = 0; it < nk; ++it) {
        const int cur = it & 1;
        __syncthreads();                          // drains vmcnt -> buf(cur) ready
        if (it + 1 < nk) issue(1 - cur, (it + 1) * 64);
        #pragma unroll
        for (int kk = 0; kk < 2; ++kk) {
            const int koff = kk * 32 + ((lane >> 4) << 3);
            bf16x8 a[2], bb[4];
            #pragma unroll
            for (int m = 0; m < 2; ++m)
                a[m] = *(const bf16x8*)&As[cur][32 * wq + 16 * m + (lane & 15)][koff];
            #pragma unroll
            for (int n = 0; n < 4; ++n)
                bb[n] = *(const bf16x8*)&Bs[cur][64 * wn + 16 * n + (lane & 15)][koff];
            #pragma unroll
            for (int m = 0; m < 2; ++m)
                #pragma unroll
                for (int n = 0; n < 4; ++n)
                    acc[m][n] = __builtin_amdgcn_mfma_f32_16x16x32_bf16(a[m], bb[n], acc[m][n], 0, 0, 0);
        }
    }

    float* Ob = Out + (size_t)b * SQ_ * DV_;
    const int rb = q0 + 32 * wq + ((lane >> 4) << 2);
    const int cb = n0 + 64 * wn + (lane & 15);
    #pragma unroll
    for (int m = 0; m < 2; ++m)
        #pragma unroll
        for (int n = 0; n < 4; ++n)
            #pragma unroll
            for (int r = 0; r < 4; ++r)
                Ob[(size_t)(rb + 16 * m + r) * DV_ + (cb + 16 * n)] = acc[m][n][r];
}

extern "C" void kernel_launch(void* const* d_in, const int* in_sizes, int n_in,
                              void* d_out, int out_size, void* d_ws, size_t ws_size,
                              hipStream_t stream) {
    (void)in_sizes; (void)n_in; (void)out_size; (void)ws_size;
    const float* Q     = (const float*)d_in[0];
    const float* K     = (const float*)d_in[1];
    const float* V     = (const float*)d_in[2];
    const int*   qlens = (const int*)d_in[3];
    const int*   klens = (const int*)d_in[4];

    float* ctx = (float*)d_out;                          // (B,SQ,DV) first
    float* wts = ctx + (size_t)B_ * SQ_ * DV_;           // then (B,SQ,SK)

    // workspace layout (ws is ~768 MB per the fill counter; we use ~100 MB)
    bf16* Vt   = (bf16*)d_ws;                            // [B][DV][SK]  32 MB
    bf16* Wb16 = Vt + (size_t)B_ * DV_ * SK_;            // [B][SQ][SK]  64 MB

    vtrans_kernel<<<dim3(SK_ / 64, DV_ / 64, B_), 256, 0, stream>>>(V, Vt);

    scores_kernel<<<dim3(SK_ / 64, SQ_ / 64, B_), 256, 0, stream>>>(Q, K, qlens, klens, wts);

    softmax_kernel<<<dim3(B_ * SQ_), 256, 0, stream>>>(qlens, klens, wts, Wb16);

    context_kernel<<<dim3(DV_ / 128, SQ_ / 128, B_), 512, 0, stream>>>(Wb16, Vt, klens, ctx);
}